// Round 7
// baseline (3225.363 us; speedup 1.0000x reference)
//
#include <hip/hip_runtime.h>

// NeuralCDE RK4 — R12: barrier-count attack (model: sync/latency-bound —
// per-stage issue work ~1/4 of the 5170-cyc stage; 13 barriers/timestep).
//   1. FUSED contraction+phase-1, z state in REGISTERS: lane (l15,q) owns
//      outputs o=q*8..q*8+7 of batch l15 == exactly phase-1's B-fragment
//      B[k=q*8+j][n=l15]. Every wave computes the full contraction
//      (redundant x4 across waves, none within a wave); za/zb + fp16 z-splits
//      live in regs. Deletes z LDS arrays + the contraction->phase-1 barrier.
//   2. dx double-buffer prefetch: coeff loads issued at s=0, written to the
//      t+1 buffer at s=3 -> staging barrier deleted, HBM latency hidden.
//   => 2 barriers/stage, 8/timestep (was 13).
// Bank layouts (analytic, <=2-way): sGf NST=52 (stores 2-way, 12xb128 reads
// 2-way per 16-lane phase, 16B-aligned); sDx stride 12 (b128 2-way).
// Per-value arithmetic order unchanged -> bit-identical (absmax 0.0).
// Everything else = R11 (fp16 2-way split MFMA: hi + 2^11-scaled residual).
// MFMA conventions = HW-verified m89/m120 mappings:
//   A[m=lane&15][k=quad*8+j], B[k=quad*8+j][n=lane&15], D[row=quad*4+r][col=lane&15]

typedef _Float16 half8 __attribute__((ext_vector_type(8)));
typedef _Float16 half4 __attribute__((ext_vector_type(4)));
typedef float floatx4 __attribute__((ext_vector_type(4)));
typedef float floatx2 __attribute__((ext_vector_type(2)));

constexpr int B_TOT  = 8192;
constexpr int L      = 256;
constexpr int CIN    = 6;
constexpr int H      = 32;
constexpr int MID    = 128;
constexpr int NSTEPS = L - 1;   // 255
constexpr int NB     = 16;      // batches per WG (one 16-row M tile)
constexpr int WG     = 256;     // 4 waves
// grid = B_TOT/NB = 512 -> 2 blocks/CU

constexpr int HP  = 152;   // h split row stride (halves): 76 dw === 12 mod 32
constexpr int NST = 52;    // sGf b-stride (floats, mult of 4: aligned b128 reads)
constexpr int DXS = 12;    // sDx inner stride (12*l15 mod 32 -> 2-way b128)
constexpr int ZP  = 33;    // final-state rows (odd)

constexpr float RSC  = 2048.f;        // 2^11 residual scale
constexpr float IRSC = 1.f / 2048.f;  // exact power of 2

__global__ __launch_bounds__(WG, 1)
void cde_hybrid_kernel(const float* __restrict__ times,
                       const float* __restrict__ coeff_b,
                       const float* __restrict__ coeff_c,
                       const float* __restrict__ coeff_d,
                       const float* __restrict__ W1g,
                       const float* __restrict__ b1g,
                       const float* __restrict__ W2g,
                       const float* __restrict__ b2g,
                       const float* __restrict__ Wlg,
                       const float* __restrict__ blg,
                       float* __restrict__ out)
{
    __shared__ __align__(16) _Float16 sHh[NB][HP], sHl[NB][HP];   // 9.5 KB
    __shared__ __align__(16) float sGf[NB * NST];                 // 3.3 KB
    __shared__ __align__(16) float sDx[2][3][NB][DXS];            // 4.6 KB
    __shared__ float sFin[NB][ZP];                                // 2.1 KB

    const int tid  = threadIdx.x;
    const int lane = tid & 63;
    const int wave = tid >> 6;      // 0..3
    const int l15  = lane & 15;
    const int q    = lane >> 4;     // 0..3
    const int b0   = blockIdx.x * NB;

    // ---- one-time: W2 fragments -> registers (fp16 hi + scaled-res), phase-2 B ----
    half8 w2h[3][4], w2l[3][4];
    float b2v[3];
    #pragma unroll
    for (int f = 0; f < 3; ++f) {
        const int n = (wave * 3 + f) * 16 + l15;
        b2v[f] = b2g[n];
        #pragma unroll
        for (int ks = 0; ks < 4; ++ks) {
            #pragma unroll
            for (int j = 0; j < 8; ++j) {
                const float w = W2g[(ks * 32 + q * 8 + j) * (H * CIN) + n];
                const _Float16 hh = (_Float16)w;
                w2h[f][ks][j] = hh;
                w2l[f][ks][j] = (_Float16)((w - (float)hh) * RSC);
            }
        }
    }

    // ---- one-time: W1^T fragments -> registers (fp16 hi + scaled-res), phase-1 A ----
    half8 w1h[2], w1l[2];
    float b1v[2][4];
    #pragma unroll
    for (int f1 = 0; f1 < 2; ++f1) {
        const int mt = wave * 2 + f1;
        #pragma unroll
        for (int j = 0; j < 8; ++j) {
            const float w = W1g[(q * 8 + j) * MID + mt * 16 + l15];
            const _Float16 hh = (_Float16)w;
            w1h[f1][j] = hh;
            w1l[f1][j] = (_Float16)((w - (float)hh) * RSC);
        }
        #pragma unroll
        for (int r = 0; r < 4; ++r)
            b1v[f1][r] = b1g[mt * 16 + q * 4 + r];   // D row = mid = mt*16+q*4+r
    }

    // ---- register z state: lane (l15,q) owns batch l15, o = q*8+0..7 ----
    float za[8], zb[8];
    half8 zh = {}, zl = {};     // fp16 splits of z (phase-1 B operand), z0 = 0
    #pragma unroll
    for (int oj = 0; oj < 8; ++oj) { za[oj] = 0.f; zb[oj] = 0.f; }

    // ---- dx staging ownership + prologue fill of buffer 0 ----
    const bool dxo = tid < NB * CIN;
    const int dxb = tid / CIN, dxi = tid - dxb * CIN;
    if (dxo) {
        const size_t off = ((size_t)(b0 + dxb) * NSTEPS + 0) * CIN + dxi;
        const float vb = coeff_b[off], vc = coeff_c[off], vd = coeff_d[off];
        const float dt0 = times[1] - times[0], f1 = 0.5f * dt0;
        sDx[0][0][dxb][dxi] = vb;
        sDx[0][1][dxb][dxi] = vb + vc * f1 + vd * f1 * f1;
        sDx[0][2][dxb][dxi] = vb + vc * dt0 + vd * dt0 * dt0;
    }
    __syncthreads();

    float pb = 0.f, pc = 0.f, pd = 0.f;   // dx prefetch registers

    for (int t = 0; t < NSTEPS; ++t) {
        const float dt = times[t + 1] - times[t];
        const int cur = t & 1;

        #pragma unroll 1
        for (int s = 0; s < 4; ++s) {
            // ---------- phase 1 (MFMA): h^T = tanh(W1^T @ z^T + b1) ----------
            // B operand = this lane's own z-splits (registers).
            floatx4 ht[2], htr[2];
            #pragma unroll
            for (int f1 = 0; f1 < 2; ++f1) {
                ht[f1]  = floatx4{0.f, 0.f, 0.f, 0.f};
                htr[f1] = floatx4{0.f, 0.f, 0.f, 0.f};
            }
            #pragma unroll
            for (int f1 = 0; f1 < 2; ++f1) {
                ht[f1]  = __builtin_amdgcn_mfma_f32_16x16x32_f16(w1h[f1], zh, ht[f1],  0, 0, 0);
                htr[f1] = __builtin_amdgcn_mfma_f32_16x16x32_f16(w1l[f1], zh, htr[f1], 0, 0, 0);
                htr[f1] = __builtin_amdgcn_mfma_f32_16x16x32_f16(w1h[f1], zl, htr[f1], 0, 0, 0);
            }
            // dx prefetch: issue loads for t+1 early (consumed at s==3)
            if (s == 0 && dxo && t + 1 < NSTEPS) {
                const size_t off = ((size_t)(b0 + dxb) * NSTEPS + (t + 1)) * CIN + dxi;
                pb = coeff_b[off]; pc = coeff_c[off]; pd = coeff_d[off];
            }
            // D[row=q*4+r][col=l15] = h^T[mid=mt*16+q*4+r][batch=l15]
            #pragma unroll
            for (int f1 = 0; f1 < 2; ++f1) {
                const int mt = wave * 2 + f1;
                half4 vh, vl;
                #pragma unroll
                for (int r = 0; r < 4; ++r) {
                    const float pre = ht[f1][r] + htr[f1][r] * IRSC + b1v[f1][r];
                    const float e = __expf(2.f * pre);        // tanh
                    const float h = 1.f - 2.f / (e + 1.f);
                    const _Float16 hh = (_Float16)h;
                    vh[r] = hh;
                    vl[r] = (_Float16)((h - (float)hh) * RSC);
                }
                *(half4*)&sHh[l15][mt * 16 + q * 4] = vh;
                *(half4*)&sHl[l15][mt * 16 + q * 4] = vl;
            }
            // dx prefetch: write t+1 buffer (ordered by B1 + later barriers)
            if (s == 3 && dxo && t + 1 < NSTEPS) {
                const float dtn = times[t + 2] - times[t + 1], f1n = 0.5f * dtn;
                sDx[cur ^ 1][0][dxb][dxi] = pb;
                sDx[cur ^ 1][1][dxb][dxi] = pb + pc * f1n + pd * f1n * f1n;
                sDx[cur ^ 1][2][dxb][dxi] = pb + pc * dtn + pd * dtn * dtn;
            }
            __syncthreads();   // B1: sH visible; also orders sGf read->write

            // ---------- phase 2 (MFMA): G = h @ W2 + b2, K=128 ----------
            floatx4 g[3], gr[3];
            #pragma unroll
            for (int f = 0; f < 3; ++f) {
                g[f]  = floatx4{0.f, 0.f, 0.f, 0.f};
                gr[f] = floatx4{0.f, 0.f, 0.f, 0.f};
            }
            #pragma unroll
            for (int ks = 0; ks < 4; ++ks) {
                const half8 ah = *(const half8*)&sHh[l15][ks * 32 + q * 8];
                const half8 al = *(const half8*)&sHl[l15][ks * 32 + q * 8];
                #pragma unroll
                for (int f = 0; f < 3; ++f) {
                    g[f]  = __builtin_amdgcn_mfma_f32_16x16x32_f16(ah, w2h[f][ks], g[f],  0, 0, 0);
                    gr[f] = __builtin_amdgcn_mfma_f32_16x16x32_f16(al, w2h[f][ks], gr[f], 0, 0, 0);
                    gr[f] = __builtin_amdgcn_mfma_f32_16x16x32_f16(ah, w2l[f][ks], gr[f], 0, 0, 0);
                }
            }
            // store [b][n], b-stride 52: bank = 16q+20r+l15+c -> 2-way (free)
            #pragma unroll
            for (int f = 0; f < 3; ++f) {
                const int n = (wave * 3 + f) * 16 + l15;
                #pragma unroll
                for (int r = 0; r < 4; ++r)
                    sGf[(q * 4 + r) * NST + n] = g[f][r] + gr[f][r] * IRSC + b2v[f];
            }
            __syncthreads();   // B2: sGf visible to all waves

            // ---------- fused contraction (redundant per wave), RK4, z-split ----------
            // lane (l15,q): batch l15, o = q*8..q*8+7; G cols n = 48q..48q+47
            const int dsel = (s == 0) ? 0 : ((s == 3) ? 2 : 1);
            const float ws = (s == 0 || s == 3) ? dt * (1.f / 6.f) : dt * (1.f / 3.f);
            floatx4 gv[12];
            #pragma unroll
            for (int c = 0; c < 12; ++c)
                gv[c] = *(const floatx4*)&sGf[l15 * NST + 48 * q + 4 * c];
            const floatx4 d04 = *(const floatx4*)&sDx[cur][dsel][l15][0];
            const floatx2 d02 = *(const floatx2*)&sDx[cur][dsel][l15][4];
            const float dx6[6] = {d04[0], d04[1], d04[2], d04[3], d02[0], d02[1]};
            #pragma unroll
            for (int oj = 0; oj < 8; ++oj) {
                float k = 0.f;
                #pragma unroll
                for (int i = 0; i < 6; ++i) {
                    const int idx = 6 * oj + i;
                    k += gv[idx >> 2][idx & 3] * dx6[i];
                }
                const float zan = za[oj] + ws * k;
                za[oj] = zan;
                float zc;
                if (s < 3) {
                    zc = zb[oj] + ((s == 2) ? dt : 0.5f * dt) * k;
                } else {
                    zb[oj] = zan;
                    zc = zan;
                }
                const _Float16 h0 = (_Float16)zc;
                zh[oj] = h0;
                zl[oj] = (_Float16)((zc - (float)h0) * RSC);
            }
            // no barrier: phase-1(s+1) uses only this lane's registers;
            // sGf/sH hazards are covered by B1/B2 of the next stage.
        }
    }

    // ---------- readout: out = zT @ Wl + bl ----------
    if (wave == 0) {
        #pragma unroll
        for (int oj = 0; oj < 8; ++oj)
            sFin[l15][q * 8 + oj] = zb[oj];
    }
    __syncthreads();
    if (tid < NB * CIN) {
        const int bb = tid / CIN, c = tid - bb * CIN;
        float acc = blg[c];
        #pragma unroll
        for (int o = 0; o < H; ++o) acc += sFin[bb][o] * Wlg[o * CIN + c];
        out[(size_t)(b0 + bb) * CIN + c] = acc;
    }
}

extern "C" void kernel_launch(void* const* d_in, const int* in_sizes, int n_in,
                              void* d_out, int out_size, void* d_ws, size_t ws_size,
                              hipStream_t stream) {
    const float* times = (const float*)d_in[0];
    // d_in[1] = coeff_a: unused by the reference vector field
    const float* cb = (const float*)d_in[2];
    const float* cc = (const float*)d_in[3];
    const float* cd = (const float*)d_in[4];
    const float* W1 = (const float*)d_in[5];
    const float* b1 = (const float*)d_in[6];
    const float* W2 = (const float*)d_in[7];
    const float* b2 = (const float*)d_in[8];
    const float* Wl = (const float*)d_in[9];
    const float* bl = (const float*)d_in[10];
    float* out = (float*)d_out;

    hipLaunchKernelGGL(cde_hybrid_kernel, dim3(B_TOT / NB), dim3(WG), 0, stream,
                       times, cb, cc, cd, W1, b1, W2, b2, Wl, bl, out);
}